// Round 1
// baseline (345.051 us; speedup 1.0000x reference)
//
#include <hip/hip_runtime.h>
#include <math.h>

#define N_LM 543
#define ROW (N_LM * 3)   // 1629 floats per row
#define L_SH 11
#define R_SH 12

__global__ __launch_bounds__(256)
void sim3_kernel(const float* __restrict__ in, float* __restrict__ out) {
    const int t = blockIdx.x;
    const float* __restrict__ row = in + (size_t)t * ROW;
    float* __restrict__ orow = out + (size_t)t * ROW;

    // Per-row params (uniform-address loads; broadcast via cache)
    const float nx = row[0], ny = row[1], nz = row[2];
    const float lsx = row[L_SH * 3 + 0], lsy = row[L_SH * 3 + 1], lsz = row[L_SH * 3 + 2];
    const float rsx = row[R_SH * 3 + 0], rsy = row[R_SH * 3 + 1], rsz = row[R_SH * 3 + 2];

    const float svx = rsx - lsx;
    const float svy = rsy - lsy;
    const float svz = rsz - lsz;

    const float s = sqrtf(svx * svx + svy * svy + svz * svz) + 1e-8f;
    const float inv_s = 1.0f / s;

    const float sxz_n = sqrtf(svx * svx + svz * svz) + 1e-8f;
    float c = svx / sxz_n;
    c = fminf(fmaxf(c, -1.0f), 1.0f);
    float st = sqrtf(fmaxf(1.0f - c * c, 0.0f));

    // |cos| > thresh -> R = I
    if (fabsf(c) > 0.9999f) { c = 1.0f; st = 0.0f; }

    // rotated[n,0] =  c*x + st*z ; [n,1] = y ; [n,2] = -st*x + c*z  (all centered, /s)
    for (int n = threadIdx.x; n < N_LM; n += blockDim.x) {
        const int o = n * 3;
        const float x = row[o + 0] - nx;
        const float y = row[o + 1] - ny;
        const float z = row[o + 2] - nz;
        orow[o + 0] = (c * x + st * z) * inv_s;
        orow[o + 1] = y * inv_s;
        orow[o + 2] = (-st * x + c * z) * inv_s;
    }
}

extern "C" void kernel_launch(void* const* d_in, const int* in_sizes, int n_in,
                              void* d_out, int out_size, void* d_ws, size_t ws_size,
                              hipStream_t stream) {
    const float* in = (const float*)d_in[0];
    float* out = (float*)d_out;
    const int T = in_sizes[0] / ROW;  // 32768
    sim3_kernel<<<T, 256, 0, stream>>>(in, out);
}